// Round 4
// baseline (772.966 us; speedup 1.0000x reference)
//
#include <hip/hip_runtime.h>
#include <hip/hip_cooperative_groups.h>
#include <math.h>

namespace cg = cooperative_groups;

#define BSZ 8
#define KG  8
#define NP  16
#define MM  64            // BS*K
#define TT  3072
#define WGN 64
#define HH  256
#define WCN 256
#define RHN 1024
#define RWN 512

#define C1H 1024
#define C1W 31
#define C2H 341
#define C2W 15
#define C3H 113
#define C3W 7

#define N1 (MM*C1H*C1W)               // 2,031,616
#define N2 (MM*C2H*C2W)               // 327,360 (per channel)
#define N3 (MM*C3H*C3W)               // 50,624
#define NF (BSZ*RHN*RWN)              // 4,194,304

#define NB 512                        // cooperative grid: 2 blocks/CU co-residency

// Stats atomic sharding: 64 slots per stat; slots of one XCD (bid&7) share a
// 64B line -> no cross-XCD line ping-pong.
#define SL 64
__device__ __forceinline__ int stat_slot(int bid) {
    return ((bid & 7) << 3) | ((bid >> 3) & 7);
}

// ---- workspace byte offsets ----
#define OFF_VINT 5376
#define OFF_Y1   (OFF_VINT + MM*HH*4)
#define OFF_Y2   (OFF_Y1  + N1*4)
#define OFF_Y3   (OFF_Y2  + 2*N2*4)
#define OFF_GENR (OFF_Y3  + N3*4)
#define OFF_Y5   (OFF_GENR + MM*RHN*4)

#define K1_R 16
#define K1_ROWS (3*K1_R)             // 48 input rows
#define K1_CH 4
#define F2_OH 32
#define F2_NCH 11                    // ceil(341/32)
#define F2_NRMAX (3*F2_OH + 4)       // 100
#define MC_TH 16
#define MC_NJ (BSZ*(RHN/MC_TH))      // 512 jobs

struct S2m { float sact[F2_NRMAX][32]; float sr3[F2_NRMAX][32]; float sr5[F2_NRMAX][32]; };
struct S4m { float tt[NP]; float vv[NP]; float tile[C3H*C3W]; };
struct S5m { float tile[MC_TH + 2][RWN + 2]; float Grow[MC_TH + 2]; };
union SMem {
    float s1[K1_ROWS * WGN];         // 12 KB
    S2m s2;                          // 38.4 KB  (max)
    S4m s4;                          // 3.3 KB
    S5m s5;                          // 37.1 KB
};

__device__ __forceinline__ void blockAdd2(double s, double ss, double* o0, double* o1) {
    __shared__ double red[4][2];
    __syncthreads();
    int lane = threadIdx.x & 63, wid = threadIdx.x >> 6;
#pragma unroll
    for (int off = 32; off > 0; off >>= 1) {
        s  += __shfl_down(s,  off, 64);
        ss += __shfl_down(ss, off, 64);
    }
    if (lane == 0) { red[wid][0] = s; red[wid][1] = ss; }
    __syncthreads();
    if (threadIdx.x == 0) {
        double a = 0, b = 0;
#pragma unroll
        for (int i = 0; i < 4; i++) { a += red[i][0]; b += red[i][1]; }
        int slot = stat_slot(blockIdx.x);
        atomicAdd(&o0[slot], a); atomicAdd(&o1[slot], b);
    }
}

// serial BN fold (fallback path)
__device__ __forceinline__ float2 bn_ab(const double* __restrict__ sums, int c,
                                        const float* __restrict__ g,
                                        const float* __restrict__ be, double n) {
    double sum = 0, sumsq = 0;
#pragma unroll 8
    for (int j = 0; j < SL; j++) {
        sum   += sums[(2 * c) * SL + j];
        sumsq += sums[(2 * c + 1) * SL + j];
    }
    double mean = sum / n;
    double var  = sumsq / n - mean * mean;
    double a = (double)g[c] / sqrt(var + 1e-5);
    return make_float2((float)a, (float)((double)be[c] - mean * a));
}

// wave-parallel BN fold (coop path): stat-pair p reduced by wave `wave`,
// result into LDS. Caller must __syncthreads() before reading *outsh.
__device__ __forceinline__ void bn_fold(const double* __restrict__ sums, int p,
                                        const float* __restrict__ g, int gc,
                                        const float* __restrict__ be,
                                        double n, float2* outsh, int wave) {
    if ((threadIdx.x >> 6) == wave) {
        int lane = threadIdx.x & 63;
        double s  = sums[(2 * p) * SL + lane];
        double ss = sums[(2 * p + 1) * SL + lane];
#pragma unroll
        for (int off = 32; off > 0; off >>= 1) {
            s  += __shfl_down(s,  off, 64);
            ss += __shfl_down(ss, off, 64);
        }
        if (lane == 0) {
            double mean = s / n;
            double var  = ss / n - mean * mean;
            double a = (double)g[gc] / sqrt(var + 1e-5);
            *outsh = make_float2((float)a, (float)((double)be[gc] - mean * a));
        }
    }
}

// ======================= cooperative all-in-one =======================
// conv1 | BN1+pool+conv2 | conv3 | vint+genr | mix+convf (regs) | BNf apply.
// The reference's x/absmax(x) norm and b1 are uniform affine transforms
// removed exactly by training-mode BN1 (LReLU/maxpool positive-homogeneous).
__global__ void __launch_bounds__(256, 2)
k_all(const float* __restrict__ gather, const float* __restrict__ cv,
      const float* __restrict__ VMM,
      const float* __restrict__ w1, const float* __restrict__ b1,
      const float* __restrict__ g1, const float* __restrict__ be1,
      const float* __restrict__ w2, const float* __restrict__ b2,
      const float* __restrict__ g2, const float* __restrict__ be2,
      const float* __restrict__ w3, const float* __restrict__ b3,
      const float* __restrict__ g3, const float* __restrict__ be3,
      const float* __restrict__ wf, const float* __restrict__ bf,
      const float* __restrict__ gf, const float* __restrict__ bef,
      float* __restrict__ out, int* __restrict__ vint,
      float* __restrict__ y1, float* __restrict__ y2, float* __restrict__ y3,
      float* __restrict__ genr, double* __restrict__ sums) {
    __shared__ SMem sm;
    __shared__ float2 absh[2];
    cg::grid_group grid = cg::this_grid();
    const int tid = threadIdx.x;
    const int bid = blockIdx.x;

    float racc[32];                  // persists across last grid sync
    int mix_b = 0, mix_h0 = 0;

    // ================= S1: conv1 + BN1 stats =================
    {
        float w[9];
#pragma unroll
        for (int i = 0; i < 9; i++) w[i] = w1[i];
        float bb = b1[0];
        double s = 0, ss = 0;
        for (int job = bid; job < MM * 64; job += NB) {
            int m = job >> 6, c = job & 63;
            const float4* src = (const float4*)(gather + (size_t)m * TT * WGN
                                                + (size_t)(c * K1_ROWS) * WGN);
            float4* dst = (float4*)sm.s1;
            dst[tid]       = src[tid];
            dst[tid + 256] = src[tid + 256];
            dst[tid + 512] = src[tid + 512];
            __syncthreads();
            float* yb = y1 + (size_t)m * C1H * C1W + (size_t)(c * K1_R) * C1W;
            for (int o = tid; o < K1_R * C1W; o += 256) {
                int lo = o / C1W, ow = o % C1W;
                const float* xp = sm.s1 + (3 * lo) * WGN + ow * 2;
                float acc = bb;
#pragma unroll
                for (int r = 0; r < 3; r++)
#pragma unroll
                    for (int cc = 0; cc < 3; cc++) acc += w[r * 3 + cc] * xp[r * WGN + cc];
                yb[o] = acc;
                s += acc; ss += (double)acc * (double)acc;
            }
            __syncthreads();
        }
        blockAdd2(s, ss, &sums[0], &sums[SL]);
    }
    __threadfence();
    grid.sync();
    __threadfence();

    // ========== S2: BN1-act + maxpool3/5 + conv2 + BN2 stats ==========
    {
        bn_fold(sums, 0, g1, 0, be1, (double)N1, &absh[0], 0);
        __syncthreads();
        float2 ab1 = absh[0];
        double s0 = 0, ss0 = 0, s1 = 0, ss1 = 0;
        for (int job = bid; job < MM * F2_NCH; job += NB) {
            int m   = job / F2_NCH;
            int ch  = job % F2_NCH;
            int oh0 = ch * F2_OH;
            int OHa = min(F2_OH, C2H - oh0);
            int NR  = 3 * OHa + 4;
            int gl0 = 3 * oh0 - 2;
            const float* yp = y1 + (size_t)m * C1H * C1W;
            for (int i = tid; i < NR * C1W; i += 256) {
                int l = i / C1W, w = i % C1W;
                int gr = gl0 + l;
                float v = -INFINITY;
                if (gr >= 0 && gr < C1H) {
                    v = ab1.x * yp[gr * C1W + w] + ab1.y;
                    v = v >= 0.f ? v : 0.1f * v;
                }
                sm.s2.sact[l][w] = v;
            }
            __syncthreads();
            for (int i = tid; i < NR * C1W; i += 256) {
                int l = i / C1W, w = i % C1W;
                int wl1 = max(w - 1, 0), wr1 = min(w + 1, C1W - 1);
                int wl2 = max(w - 2, 0), wr2 = min(w + 2, C1W - 1);
                float c  = sm.s2.sact[l][w];
                float m3 = fmaxf(fmaxf(sm.s2.sact[l][wl1], c), sm.s2.sact[l][wr1]);
                float m5 = fmaxf(fmaxf(m3, sm.s2.sact[l][wl2]), sm.s2.sact[l][wr2]);
                sm.s2.sr3[l][w] = m3;
                sm.s2.sr5[l][w] = m5;
            }
            __syncthreads();
            for (int o = tid; o < OHa * C2W; o += 256) {
                int lo = o / C2W, ow = o % C2W;
                float a0 = b2[0], acc1 = b2[1];
#pragma unroll
                for (int i = 0; i < 3; i++) {
                    int l = 3 * lo + 2 + i;
#pragma unroll
                    for (int j = 0; j < 3; j++) {
                        int wc = 2 * ow + j;
                        float v0 = sm.s2.sact[l][wc];
                        float v1 = fmaxf(fmaxf(sm.s2.sr3[l - 1][wc], sm.s2.sr3[l][wc]),
                                         sm.s2.sr3[l + 1][wc]);
                        float v2 = fmaxf(fmaxf(fmaxf(sm.s2.sr5[l - 2][wc], sm.s2.sr5[l - 1][wc]),
                                               sm.s2.sr5[l][wc]),
                                         fmaxf(sm.s2.sr5[l + 1][wc], sm.s2.sr5[l + 2][wc]));
                        int ki = i * 3 + j;
                        a0   += w2[ki] * v0 + w2[9 + ki] * v1 + w2[18 + ki] * v2;
                        acc1 += w2[27 + ki] * v0 + w2[36 + ki] * v1 + w2[45 + ki] * v2;
                    }
                }
                size_t ob = (size_t)m * (2 * C2H * C2W) + (size_t)(oh0 + lo) * C2W + ow;
                y2[ob] = a0;
                y2[ob + C2H * C2W] = acc1;
                s0 += a0; ss0 += (double)a0 * a0;
                s1 += acc1; ss1 += (double)acc1 * acc1;
            }
            __syncthreads();
        }
        blockAdd2(s0, ss0, &sums[2 * SL], &sums[3 * SL]);
        blockAdd2(s1, ss1, &sums[4 * SL], &sums[5 * SL]);
    }
    __threadfence();
    grid.sync();
    __threadfence();

    // ========== S3: conv3 (BN2-act inline) + BN3 stats ==========
    {
        bn_fold(sums, 1, g2, 0, be2, (double)N2, &absh[0], 0);
        bn_fold(sums, 2, g2, 1, be2, (double)N2, &absh[1], 1);
        __syncthreads();
        float2 ab20 = absh[0], ab21 = absh[1];
        double s = 0, ss = 0;
        for (int idx = bid * 256 + tid; idx < N3; idx += NB * 256) {
            int ow = idx % C3W;
            int t2 = idx / C3W;
            int oh = t2 % C3H;
            int m  = t2 / C3H;
            float acc = b3[0];
#pragma unroll
            for (int i = 0; i < 2; i++) {
                float aa = i ? ab21.x : ab20.x, bb = i ? ab21.y : ab20.y;
                const float* cp = y2 + (size_t)m * (2 * C2H * C2W) + (size_t)i * C2H * C2W
                                  + (size_t)(oh * 3) * C2W + ow * 2;
#pragma unroll
                for (int r = 0; r < 3; r++)
#pragma unroll
                    for (int c = 0; c < 2; c++) {
                        float v = aa * cp[r * C2W + c] + bb;
                        v = v >= 0.f ? v : 0.1f * v;
                        acc += w3[i * 6 + r * 2 + c] * v;
                    }
            }
            y3[idx] = acc;
            s += acc; ss += (double)acc * acc;
        }
        blockAdd2(s, ss, &sums[6 * SL], &sums[7 * SL]);
    }
    __threadfence();
    grid.sync();
    __threadfence();

    // ========== S4: vint (interp) + BN3-act + resize -> genr ==========
    if (bid < MM) {
        bn_fold(sums, 3, g3, 0, be3, (double)N3, &absh[0], 0);
        __syncthreads();
        float2 ab3 = absh[0];
        int m = bid;
        int b = m >> 3;
        if (tid < NP) {
            int n = tid;
            float t = cv[(m * NP + n) * 2 + 0];
            float v = cv[(m * NP + n) * 2 + 1];
            float dt = 7000.0f / 255.0f;
            sm.s4.tt[n] = t / dt;
            float vmin = VMM[b * 2], vmax = VMM[b * 2 + 1];
            float dv = (vmax - vmin) / 255.0f;
            sm.s4.vv[n] = (v - vmin) / dv;
        }
        for (int i = tid; i < C3H * C3W; i += 256) {
            float v = ab3.x * y3[m * C3H * C3W + i] + ab3.y;
            sm.s4.tile[i] = v >= 0.f ? v : 0.1f * v;
        }
        __syncthreads();
        {   // vint: one thread per h
            int h = tid;
            float x = (float)h;
            float val;
            if (x <= sm.s4.tt[0]) val = sm.s4.vv[0];
            else if (x >= sm.s4.tt[NP - 1]) val = sm.s4.vv[NP - 1];
            else {
                int i = 1;
                while (i < NP - 1 && sm.s4.tt[i] <= x) i++;
                float d = sm.s4.tt[i] - sm.s4.tt[i - 1];
                val = (d != 0.f) ? sm.s4.vv[i - 1] + (x - sm.s4.tt[i - 1]) / d *
                                   (sm.s4.vv[i] - sm.s4.vv[i - 1])
                                 : sm.s4.vv[i];
            }
            int vi = (int)val;
            vint[m * HH + h] = max(0, min(WCN - 1, vi));
        }
        const float cw0 = 4.f / 37.f, cw1 = 5.f / 37.f, cw2 = 6.f / 37.f, cw3 = 7.f / 37.f;
        const float cw[7] = { cw0, cw1, cw2, cw3, cw2, cw1, cw0 };
        for (int i = tid; i < RHN; i += 256) {
            float sh = (i + 0.5f) * (113.0f / 1024.0f) - 0.5f;
            float fl = floorf(sh);
            float fr = sh - fl;
            int i0 = (int)fl, i1 = i0 + 1;
            i0 = max(0, min(C3H - 1, i0));
            i1 = max(0, min(C3H - 1, i1));
            float acc = 0.f;
#pragma unroll
            for (int x = 0; x < 7; x++) {
                float v = (1.f - fr) * sm.s4.tile[i0 * C3W + x] + fr * sm.s4.tile[i1 * C3W + x];
                acc += cw[x] * v;
            }
            genr[m * RHN + i] = acc;
        }
    }
    __threadfence();
    grid.sync();
    __threadfence();

    // ========== S5: mix tile + convf (acc in regs) + BNf stats ==========
    if (bid < MC_NJ) {
        mix_b  = bid / (RHN / MC_TH);
        mix_h0 = (bid % (RHN / MC_TH)) * MC_TH;
        for (int i = tid; i < (MC_TH + 2) * (RWN + 2); i += 256)
            ((float*)sm.s5.tile)[i] = 0.f;
        if (tid < MC_TH + 2) sm.s5.Grow[tid] = 0.f;
        __syncthreads();
        if (tid < (MC_TH + 2) * KG) {
            int r = tid / KG, k = tid % KG;
            int h = mix_h0 - 1 + r;
            if (h >= 0 && h < RHN) {
                int m = mix_b * KG + k;
                float g = genr[m * RHN + h];
                atomicAdd(&sm.s5.Grow[r], g);
                float sh = (h + 0.5f) * 0.25f - 0.5f;
                float fl = floorf(sh);
                float fh = sh - fl;
                int ih0 = (int)fl, ih1 = ih0 + 1;
                ih0 = max(0, min(HH - 1, ih0));
                ih1 = max(0, min(HH - 1, ih1));
                int vv2[2] = { vint[m * HH + ih0], vint[m * HH + ih1] };
                float aa[2] = { 0.9f * g * (1.f - fh), 0.9f * g * fh };
#pragma unroll
                for (int t = 0; t < 2; t++) {
                    int v = vv2[t]; float A = aa[t];
                    if (v == 0) {
                        atomicAdd(&sm.s5.tile[r][1 + 0], A);
                        atomicAdd(&sm.s5.tile[r][1 + 1], 0.75f * A);
                        atomicAdd(&sm.s5.tile[r][1 + 2], 0.25f * A);
                    } else if (v == WCN - 1) {
                        atomicAdd(&sm.s5.tile[r][1 + 509], 0.25f * A);
                        atomicAdd(&sm.s5.tile[r][1 + 510], 0.75f * A);
                        atomicAdd(&sm.s5.tile[r][1 + 511], A);
                    } else {
                        atomicAdd(&sm.s5.tile[r][1 + 2 * v - 1], 0.25f * A);
                        atomicAdd(&sm.s5.tile[r][1 + 2 * v],     0.75f * A);
                        atomicAdd(&sm.s5.tile[r][1 + 2 * v + 1], 0.75f * A);
                        atomicAdd(&sm.s5.tile[r][1 + 2 * v + 2], 0.25f * A);
                    }
                }
            }
        }
        __syncthreads();
        for (int i = tid; i < (MC_TH + 2) * RWN; i += 256) {
            int r = i / RWN, w = i % RWN;
            int h = mix_h0 - 1 + r;
            if (h >= 0 && h < RHN) sm.s5.tile[r][w + 1] += 0.01f * sm.s5.Grow[r];
        }
        __syncthreads();
        float w[9];
#pragma unroll
        for (int i = 0; i < 9; i++) w[i] = wf[i];
        float bb = bf[0];
        double s = 0, ss = 0;
#pragma unroll
        for (int it = 0; it < 32; ++it) {
            int o = tid + it * 256;
            int lr = o >> 9, x = o & (RWN - 1);
            float acc = bb;
#pragma unroll
            for (int dr = 0; dr < 3; dr++)
#pragma unroll
                for (int dc = 0; dc < 3; dc++)
                    acc += w[dr * 3 + dc] * sm.s5.tile[lr + dr][x + dc];
            racc[it] = acc;
            s += acc; ss += (double)acc * acc;
        }
        blockAdd2(s, ss, &sums[8 * SL], &sums[9 * SL]);
    }
    __threadfence();
    grid.sync();
    __threadfence();

    // ========== S6: BNf affine + LReLU from registers -> out ==========
    bn_fold(sums, 4, gf, 0, bef, (double)NF, &absh[0], 0);
    __syncthreads();
    if (bid < MC_NJ) {
        float2 abf = absh[0];
#pragma unroll
        for (int it = 0; it < 32; ++it) {
            int o = tid + it * 256;
            int lr = o >> 9, x = o & (RWN - 1);
            float v = abf.x * racc[it] + abf.y;
            out[((size_t)mix_b * RHN + (mix_h0 + lr)) * RWN + x] = v >= 0.f ? v : 0.1f * v;
        }
    }
}

// ======================= fallback kernels (round-2, known-good) =======================
__global__ void k_conv1_fb(const float* __restrict__ g, const float* __restrict__ w1,
                           const float* __restrict__ b1,
                           float* __restrict__ y1, double* sums) {
    __shared__ float sm[K1_ROWS * WGN];
    int m  = blockIdx.x >> 4;
    int bg = blockIdx.x & 15;
    const float4* src0 = (const float4*)(g + (size_t)m * TT * WGN
                                           + (size_t)(bg * K1_CH * K1_R * 3) * WGN);
    float w[9];
#pragma unroll
    for (int i = 0; i < 9; i++) w[i] = w1[i];
    float bb = b1[0];
    float4 ra0, ra1, ra2, rb0, rb1, rb2;
    ra0 = src0[threadIdx.x];
    ra1 = src0[threadIdx.x + 256];
    ra2 = src0[threadIdx.x + 512];
    double s = 0, ss = 0;
    float4* dst = (float4*)sm;
#pragma unroll
    for (int i = 0; i < K1_CH; i++) {
        if (i & 1) {
            dst[threadIdx.x]       = rb0;
            dst[threadIdx.x + 256] = rb1;
            dst[threadIdx.x + 512] = rb2;
        } else {
            dst[threadIdx.x]       = ra0;
            dst[threadIdx.x + 256] = ra1;
            dst[threadIdx.x + 512] = ra2;
        }
        __syncthreads();
        if (i + 1 < K1_CH) {
            const float4* srcn = src0 + (size_t)(i + 1) * 768;
            if (i & 1) {
                ra0 = srcn[threadIdx.x];
                ra1 = srcn[threadIdx.x + 256];
                ra2 = srcn[threadIdx.x + 512];
            } else {
                rb0 = srcn[threadIdx.x];
                rb1 = srcn[threadIdx.x + 256];
                rb2 = srcn[threadIdx.x + 512];
            }
        }
        int oh0 = (bg * K1_CH + i) * K1_R;
        float* yb = y1 + (size_t)m * C1H * C1W + (size_t)oh0 * C1W;
        for (int o = threadIdx.x; o < K1_R * C1W; o += 256) {
            int lo = o / C1W, ow = o % C1W;
            const float* xp = sm + (3 * lo) * WGN + ow * 2;
            float acc = bb;
#pragma unroll
            for (int r = 0; r < 3; r++)
#pragma unroll
                for (int c = 0; c < 3; c++) acc += w[r * 3 + c] * xp[r * WGN + c];
            yb[o] = acc;
            s += acc; ss += (double)acc * (double)acc;
        }
        __syncthreads();
    }
    blockAdd2(s, ss, &sums[0], &sums[SL]);
}

__global__ void k_fused2_fb(const float* __restrict__ y1, const double* __restrict__ sums_r,
                            const float* __restrict__ g1, const float* __restrict__ be1,
                            const float* __restrict__ w2, const float* __restrict__ b2,
                            float* __restrict__ y2, double* sums) {
    __shared__ float sact[F2_NRMAX][32];
    __shared__ float sr3[F2_NRMAX][32];
    __shared__ float sr5[F2_NRMAX][32];
    float2 ab1 = bn_ab(sums_r, 0, g1, be1, (double)N1);
    int m   = blockIdx.x / F2_NCH;
    int ch  = blockIdx.x % F2_NCH;
    int oh0 = ch * F2_OH;
    int OHa = min(F2_OH, C2H - oh0);
    int NR  = 3 * OHa + 4;
    int gl0 = 3 * oh0 - 2;
    const float* yp = y1 + (size_t)m * C1H * C1W;
    for (int i = threadIdx.x; i < NR * C1W; i += blockDim.x) {
        int l = i / C1W, w = i % C1W;
        int gr = gl0 + l;
        float v = -INFINITY;
        if (gr >= 0 && gr < C1H) {
            v = ab1.x * yp[gr * C1W + w] + ab1.y;
            v = v >= 0.f ? v : 0.1f * v;
        }
        sact[l][w] = v;
    }
    __syncthreads();
    for (int i = threadIdx.x; i < NR * C1W; i += blockDim.x) {
        int l = i / C1W, w = i % C1W;
        int wl1 = max(w - 1, 0), wr1 = min(w + 1, C1W - 1);
        int wl2 = max(w - 2, 0), wr2 = min(w + 2, C1W - 1);
        float c  = sact[l][w];
        float m3 = fmaxf(fmaxf(sact[l][wl1], c), sact[l][wr1]);
        float m5 = fmaxf(fmaxf(m3, sact[l][wl2]), sact[l][wr2]);
        sr3[l][w] = m3;
        sr5[l][w] = m5;
    }
    __syncthreads();
    double s0 = 0, ss0 = 0, s1 = 0, ss1 = 0;
    for (int o = threadIdx.x; o < OHa * C2W; o += blockDim.x) {
        int lo = o / C2W, ow = o % C2W;
        float a0 = b2[0], acc1 = b2[1];
#pragma unroll
        for (int i = 0; i < 3; i++) {
            int l = 3 * lo + 2 + i;
#pragma unroll
            for (int j = 0; j < 3; j++) {
                int wc = 2 * ow + j;
                float v0 = sact[l][wc];
                float v1 = fmaxf(fmaxf(sr3[l - 1][wc], sr3[l][wc]), sr3[l + 1][wc]);
                float v2 = fmaxf(fmaxf(fmaxf(sr5[l - 2][wc], sr5[l - 1][wc]), sr5[l][wc]),
                                 fmaxf(sr5[l + 1][wc], sr5[l + 2][wc]));
                int ki = i * 3 + j;
                a0   += w2[ki] * v0 + w2[9 + ki] * v1 + w2[18 + ki] * v2;
                acc1 += w2[27 + ki] * v0 + w2[36 + ki] * v1 + w2[45 + ki] * v2;
            }
        }
        size_t ob = (size_t)m * (2 * C2H * C2W) + (size_t)(oh0 + lo) * C2W + ow;
        y2[ob] = a0;
        y2[ob + C2H * C2W] = acc1;
        s0 += a0; ss0 += (double)a0 * a0;
        s1 += acc1; ss1 += (double)acc1 * acc1;
    }
    blockAdd2(s0, ss0, &sums[2 * SL], &sums[3 * SL]);
    blockAdd2(s1, ss1, &sums[4 * SL], &sums[5 * SL]);
}

__global__ void k_conv3_fb(const float* __restrict__ y2, const double* __restrict__ sums_r,
                           const float* __restrict__ g2, const float* __restrict__ be2,
                           const float* __restrict__ w3, const float* __restrict__ b3,
                           float* __restrict__ y3, double* sums) {
    float2 ab20 = bn_ab(sums_r + 2 * SL, 0, g2, be2, (double)N2);
    float2 ab21 = bn_ab(sums_r + 2 * SL, 1, g2, be2, (double)N2);
    double s = 0, ss = 0;
    int stride = gridDim.x * blockDim.x;
    for (int idx = blockIdx.x * blockDim.x + threadIdx.x; idx < N3; idx += stride) {
        int ow = idx % C3W;
        int t2 = idx / C3W;
        int oh = t2 % C3H;
        int m  = t2 / C3H;
        float acc = b3[0];
#pragma unroll
        for (int i = 0; i < 2; i++) {
            float aa = i ? ab21.x : ab20.x, bb = i ? ab21.y : ab20.y;
            const float* cp = y2 + (size_t)m * (2 * C2H * C2W) + (size_t)i * C2H * C2W
                              + (size_t)(oh * 3) * C2W + ow * 2;
#pragma unroll
            for (int r = 0; r < 3; r++)
#pragma unroll
                for (int c = 0; c < 2; c++) {
                    float v = aa * cp[r * C2W + c] + bb;
                    v = v >= 0.f ? v : 0.1f * v;
                    acc += w3[i * 6 + r * 2 + c] * v;
                }
        }
        y3[idx] = acc;
        s += acc; ss += (double)acc * acc;
    }
    blockAdd2(s, ss, &sums[6 * SL], &sums[7 * SL]);
}

__global__ void k_vintgenr_fb(const float* __restrict__ cv, const float* __restrict__ VMM,
                              const float* __restrict__ y3, const double* __restrict__ sums_r,
                              const float* __restrict__ g3, const float* __restrict__ be3,
                              int* __restrict__ vint, float* __restrict__ genr) {
    __shared__ float tt[NP], vv[NP];
    __shared__ float tile[C3H * C3W];
    int m = blockIdx.x;
    int b = m >> 3;
    float2 ab3 = bn_ab(sums_r + 6 * SL, 0, g3, be3, (double)N3);
    if (threadIdx.x < NP) {
        int n = threadIdx.x;
        float t = cv[(m * NP + n) * 2 + 0];
        float v = cv[(m * NP + n) * 2 + 1];
        float dt = 7000.0f / 255.0f;
        tt[n] = t / dt;
        float vmin = VMM[b * 2], vmax = VMM[b * 2 + 1];
        float dv = (vmax - vmin) / 255.0f;
        vv[n] = (v - vmin) / dv;
    }
    for (int i = threadIdx.x; i < C3H * C3W; i += blockDim.x) {
        float v = ab3.x * y3[m * C3H * C3W + i] + ab3.y;
        tile[i] = v >= 0.f ? v : 0.1f * v;
    }
    __syncthreads();
    {
        int h = threadIdx.x;
        float x = (float)h;
        float val;
        if (x <= tt[0]) val = vv[0];
        else if (x >= tt[NP - 1]) val = vv[NP - 1];
        else {
            int i = 1;
            while (i < NP - 1 && tt[i] <= x) i++;
            float d = tt[i] - tt[i - 1];
            val = (d != 0.f) ? vv[i - 1] + (x - tt[i - 1]) / d * (vv[i] - vv[i - 1]) : vv[i];
        }
        int vi = (int)val;
        vint[m * HH + h] = max(0, min(WCN - 1, vi));
    }
    const float cw0 = 4.f / 37.f, cw1 = 5.f / 37.f, cw2 = 6.f / 37.f, cw3 = 7.f / 37.f;
    const float cw[7] = { cw0, cw1, cw2, cw3, cw2, cw1, cw0 };
    for (int i = threadIdx.x; i < RHN; i += blockDim.x) {
        float sh = (i + 0.5f) * (113.0f / 1024.0f) - 0.5f;
        float fl = floorf(sh);
        float fr = sh - fl;
        int i0 = (int)fl, i1 = i0 + 1;
        i0 = max(0, min(C3H - 1, i0));
        i1 = max(0, min(C3H - 1, i1));
        float acc = 0.f;
#pragma unroll
        for (int x = 0; x < 7; x++) {
            float v = (1.f - fr) * tile[i0 * C3W + x] + fr * tile[i1 * C3W + x];
            acc += cw[x] * v;
        }
        genr[m * RHN + i] = acc;
    }
}

__device__ __forceinline__ void build_mix_tile_fb(const float* __restrict__ genr,
                                                  const int* __restrict__ vint,
                                                  int b, int h0,
                                                  float (*tile)[RWN + 2], float* Grow) {
    for (int i = threadIdx.x; i < (MC_TH + 2) * (RWN + 2); i += blockDim.x)
        ((float*)tile)[i] = 0.f;
    if (threadIdx.x < MC_TH + 2) Grow[threadIdx.x] = 0.f;
    __syncthreads();
    if (threadIdx.x < (MC_TH + 2) * KG) {
        int r = threadIdx.x / KG, k = threadIdx.x % KG;
        int h = h0 - 1 + r;
        if (h >= 0 && h < RHN) {
            int m = b * KG + k;
            float g = genr[m * RHN + h];
            atomicAdd(&Grow[r], g);
            float sh = (h + 0.5f) * 0.25f - 0.5f;
            float fl = floorf(sh);
            float fh = sh - fl;
            int ih0 = (int)fl, ih1 = ih0 + 1;
            ih0 = max(0, min(HH - 1, ih0));
            ih1 = max(0, min(HH - 1, ih1));
            int vv[2] = { vint[m * HH + ih0], vint[m * HH + ih1] };
            float aa[2] = { 0.9f * g * (1.f - fh), 0.9f * g * fh };
#pragma unroll
            for (int t = 0; t < 2; t++) {
                int v = vv[t]; float A = aa[t];
                if (v == 0) {
                    atomicAdd(&tile[r][1 + 0], A);
                    atomicAdd(&tile[r][1 + 1], 0.75f * A);
                    atomicAdd(&tile[r][1 + 2], 0.25f * A);
                } else if (v == WCN - 1) {
                    atomicAdd(&tile[r][1 + 509], 0.25f * A);
                    atomicAdd(&tile[r][1 + 510], 0.75f * A);
                    atomicAdd(&tile[r][1 + 511], A);
                } else {
                    atomicAdd(&tile[r][1 + 2 * v - 1], 0.25f * A);
                    atomicAdd(&tile[r][1 + 2 * v],     0.75f * A);
                    atomicAdd(&tile[r][1 + 2 * v + 1], 0.75f * A);
                    atomicAdd(&tile[r][1 + 2 * v + 2], 0.25f * A);
                }
            }
        }
    }
    __syncthreads();
    for (int i = threadIdx.x; i < (MC_TH + 2) * RWN; i += blockDim.x) {
        int r = i / RWN, w = i % RWN;
        int h = h0 - 1 + r;
        if (h >= 0 && h < RHN) tile[r][w + 1] += 0.01f * Grow[r];
    }
    __syncthreads();
}

__global__ void k_mixA_fb(const float* __restrict__ genr, const int* __restrict__ vint,
                          const float* __restrict__ wf, const float* __restrict__ bf,
                          float* __restrict__ y5, double* sums) {
    __shared__ float tile[MC_TH + 2][RWN + 2];
    __shared__ float Grow[MC_TH + 2];
    int b   = blockIdx.x / (RHN / MC_TH);
    int h0  = (blockIdx.x % (RHN / MC_TH)) * MC_TH;
    build_mix_tile_fb(genr, vint, b, h0, tile, Grow);
    float w[9];
#pragma unroll
    for (int i = 0; i < 9; i++) w[i] = wf[i];
    float bb = bf[0];
    double s = 0, ss = 0;
    for (int o = threadIdx.x; o < MC_TH * RWN; o += blockDim.x) {
        int lr = o / RWN, x = o % RWN;
        float acc = bb;
#pragma unroll
        for (int dr = 0; dr < 3; dr++)
#pragma unroll
            for (int dc = 0; dc < 3; dc++)
                acc += w[dr * 3 + dc] * tile[lr + dr][x + dc];
        y5[((size_t)b * RHN + (h0 + lr)) * RWN + x] = acc;
        s += acc; ss += (double)acc * acc;
    }
    blockAdd2(s, ss, &sums[8 * SL], &sums[9 * SL]);
}

__global__ void k_bnf_fb(const float* __restrict__ y5, const double* __restrict__ sums_r,
                         const float* __restrict__ gf, const float* __restrict__ bef,
                         float* __restrict__ out) {
    float2 abf = bn_ab(sums_r + 8 * SL, 0, gf, bef, (double)NF);
    int stride = gridDim.x * blockDim.x;
    const float4* src = (const float4*)y5;
    float4* dst = (float4*)out;
    for (int i = blockIdx.x * blockDim.x + threadIdx.x; i < NF / 4; i += stride) {
        float4 v = src[i];
        float a0 = abf.x * v.x + abf.y;
        float a1 = abf.x * v.y + abf.y;
        float a2 = abf.x * v.z + abf.y;
        float a3 = abf.x * v.w + abf.y;
        v.x = a0 >= 0.f ? a0 : 0.1f * a0;
        v.y = a1 >= 0.f ? a1 : 0.1f * a1;
        v.z = a2 >= 0.f ? a2 : 0.1f * a2;
        v.w = a3 >= 0.f ? a3 : 0.1f * a3;
        dst[i] = v;
    }
}

// ======================= host launcher =======================
static int g_mode = -1;   // -1 = undecided, 1 = cooperative, 0 = fallback

extern "C" void kernel_launch(void* const* d_in, const int* in_sizes, int n_in,
                              void* d_out, int out_size, void* d_ws, size_t ws_size,
                              hipStream_t stream) {
    const float* gather = (const float*)d_in[0];
    const float* cv     = (const float*)d_in[1];
    const float* VMM    = (const float*)d_in[2];
    const float* w1 = (const float*)d_in[3];
    const float* b1 = (const float*)d_in[4];
    const float* g1 = (const float*)d_in[5];
    const float* be1 = (const float*)d_in[6];
    const float* w2 = (const float*)d_in[7];
    const float* b2 = (const float*)d_in[8];
    const float* g2 = (const float*)d_in[9];
    const float* be2 = (const float*)d_in[10];
    const float* w3 = (const float*)d_in[11];
    const float* b3 = (const float*)d_in[12];
    const float* g3 = (const float*)d_in[13];
    const float* be3 = (const float*)d_in[14];
    const float* wf = (const float*)d_in[15];
    const float* bf = (const float*)d_in[16];
    const float* gf = (const float*)d_in[17];
    const float* bef = (const float*)d_in[18];
    float* out = (float*)d_out;

    char* ws = (char*)d_ws;
    double* sums = (double*)ws;
    int*   vint  = (int*)(ws + OFF_VINT);
    float* y1    = (float*)(ws + OFF_Y1);
    float* y2    = (float*)(ws + OFF_Y2);
    float* y3    = (float*)(ws + OFF_Y3);
    float* genr  = (float*)(ws + OFF_GENR);
    float* y5    = (float*)(ws + OFF_Y5);

    hipMemsetAsync(d_ws, 0, 10 * SL * 8, stream);

    if (g_mode == -1) {
        int nb = 0;
        hipError_t e = hipOccupancyMaxActiveBlocksPerMultiprocessor(&nb, k_all, 256, 0);
        g_mode = (e == hipSuccess && nb >= 2) ? 1 : 0;
        (void)hipGetLastError();
    }
    if (g_mode == 1) {
        void* args[] = {
            (void*)&gather, (void*)&cv, (void*)&VMM,
            (void*)&w1, (void*)&b1, (void*)&g1, (void*)&be1,
            (void*)&w2, (void*)&b2, (void*)&g2, (void*)&be2,
            (void*)&w3, (void*)&b3, (void*)&g3, (void*)&be3,
            (void*)&wf, (void*)&bf, (void*)&gf, (void*)&bef,
            (void*)&out, (void*)&vint,
            (void*)&y1, (void*)&y2, (void*)&y3, (void*)&genr, (void*)&sums
        };
        hipError_t err = hipLaunchCooperativeKernel(reinterpret_cast<void*>(k_all),
                                                    dim3(NB), dim3(256), args, 0, stream);
        if (err != hipSuccess) {
            g_mode = 0;
            (void)hipGetLastError();
        }
    }
    if (g_mode == 0) {
        k_conv1_fb<<<MM * 16, 256, 0, stream>>>(gather, w1, b1, y1, sums);
        k_fused2_fb<<<MM * F2_NCH, 256, 0, stream>>>(y1, sums, g1, be1, w2, b2, y2, sums);
        k_conv3_fb<<<198, 256, 0, stream>>>(y2, sums, g2, be2, w3, b3, y3, sums);
        k_vintgenr_fb<<<MM, 256, 0, stream>>>(cv, VMM, y3, sums, g3, be3, vint, genr);
        k_mixA_fb<<<BSZ * (RHN / MC_TH), 256, 0, stream>>>(genr, vint, wf, bf, y5, sums);
        k_bnf_fb<<<2048, 256, 0, stream>>>(y5, sums, gf, bef, out);
    }
}

// Round 5
// 174.711 us; speedup vs baseline: 4.4243x; 4.4243x over previous
//
#include <hip/hip_runtime.h>
#include <math.h>

#define BSZ 8
#define KG  8
#define NP  16
#define MM  64            // BS*K
#define TT  3072
#define WGN 64
#define HH  256
#define WCN 256
#define RHN 1024
#define RWN 512

#define C1H 1024
#define C1W 31
#define C2H 341
#define C2W 15
#define C3H 113
#define C3W 7

#define N1 (MM*C1H*C1W)               // 2,031,616
#define N2 (MM*C2H*C2W)               // 327,360 (per channel)
#define N3 (MM*C3H*C3W)               // 50,624
#define NF (BSZ*RHN*RWN)              // 4,194,304

// ---- grids (fixed: partial-slot counts depend on them) ----
#define G1 1024
#define G2 704                        // MM * ceil(341/32)
#define G3 256
#define G5 512
#define G6 512

// ---- partial-sum slots (doubles), plain stores - no atomics, no memset ----
#define P1S   0
#define P1SS  1024
#define P2S0  2048
#define P2SS0 2752
#define P2S1  3456
#define P2SS1 4160
#define P3S   4864
#define P3SS  5120
#define PFS   5376
#define PFSS  5888
// total 6400 doubles = 51200 B

#define OFF_VINT 51200
#define OFF_Y1   (OFF_VINT + MM*HH*4)
#define OFF_Y2   (OFF_Y1  + N1*4)
#define OFF_Y3   (OFF_Y2  + 2*N2*4)
#define OFF_Y5   (OFF_Y3  + N3*4)

#define K1_R 16
#define K1_ROWS (3*K1_R)             // 48 input rows
#define K1_CH 4
#define F2_OH 32
#define F2_NCH 11                    // ceil(341/32)
#define F2_NRMAX (3*F2_OH + 4)       // 100
#define MC_TH 16

// block-reduce (s,ss) then ONE plain store per block into slot bid.
__device__ __forceinline__ void blockStore2(double s, double ss,
                                            double* __restrict__ o0,
                                            double* __restrict__ o1) {
    __shared__ double red[4][2];
    __syncthreads();
    int lane = threadIdx.x & 63, wid = threadIdx.x >> 6;
#pragma unroll
    for (int off = 32; off > 0; off >>= 1) {
        s  += __shfl_down(s,  off, 64);
        ss += __shfl_down(ss, off, 64);
    }
    if (lane == 0) { red[wid][0] = s; red[wid][1] = ss; }
    __syncthreads();
    if (threadIdx.x == 0) {
        double a = 0, b = 0;
#pragma unroll
        for (int i = 0; i < 4; i++) { a += red[i][0]; b += red[i][1]; }
        o0[blockIdx.x] = a; o1[blockIdx.x] = b;
    }
}

// wave `wave` reduces `npart` partials and writes folded BN (a,b) to *outsh.
// Caller must __syncthreads() before reading *outsh.
__device__ __forceinline__ void bn_fold(const double* __restrict__ ps,
                                        const double* __restrict__ pss,
                                        int npart, const float* __restrict__ g, int gc,
                                        const float* __restrict__ be,
                                        double n, float2* outsh, int wave) {
    if ((threadIdx.x >> 6) == wave) {
        int lane = threadIdx.x & 63;
        double s = 0, ss = 0;
        for (int i = lane; i < npart; i += 64) { s += ps[i]; ss += pss[i]; }
#pragma unroll
        for (int off = 32; off > 0; off >>= 1) {
            s  += __shfl_down(s,  off, 64);
            ss += __shfl_down(ss, off, 64);
        }
        if (lane == 0) {
            double mean = s / n;
            double var  = ss / n - mean * mean;
            double a = (double)g[gc] / sqrt(var + 1e-5);
            *outsh = make_float2((float)a, (float)((double)be[gc] - mean * a));
        }
    }
}

// ---- K1: conv1 (1x1x3x3, stride 3x2, VALID) + BN1 partials; blocks 0..63
// also compute vint (cv interp - independent of conv path). The reference's
// x/absmax(x) norm and b1 are uniform affine transforms removed exactly by
// training-mode BN1 (LReLU/maxpool positive-homogeneous).
__global__ void k_conv1(const float* __restrict__ g, const float* __restrict__ cv,
                        const float* __restrict__ VMM, const float* __restrict__ w1,
                        const float* __restrict__ b1,
                        float* __restrict__ y1, int* __restrict__ vint,
                        double* __restrict__ sums) {
    __shared__ float sm[K1_ROWS * WGN];       // 12 KB
    __shared__ float tt[NP], vv[NP];
    int m  = blockIdx.x >> 4;
    int bg = blockIdx.x & 15;
    const float4* src0 = (const float4*)(g + (size_t)m * TT * WGN
                                           + (size_t)(bg * K1_CH * K1_R * 3) * WGN);
    float w[9];
#pragma unroll
    for (int i = 0; i < 9; i++) w[i] = w1[i];
    float bb = b1[0];
    float4 ra0, ra1, ra2, rb0, rb1, rb2;
    ra0 = src0[threadIdx.x];
    ra1 = src0[threadIdx.x + 256];
    ra2 = src0[threadIdx.x + 512];
    double s = 0, ss = 0;
    float4* dst = (float4*)sm;
#pragma unroll
    for (int i = 0; i < K1_CH; i++) {
        if (i & 1) {
            dst[threadIdx.x]       = rb0;
            dst[threadIdx.x + 256] = rb1;
            dst[threadIdx.x + 512] = rb2;
        } else {
            dst[threadIdx.x]       = ra0;
            dst[threadIdx.x + 256] = ra1;
            dst[threadIdx.x + 512] = ra2;
        }
        __syncthreads();
        if (i + 1 < K1_CH) {
            const float4* srcn = src0 + (size_t)(i + 1) * 768;
            if (i & 1) {
                ra0 = srcn[threadIdx.x];
                ra1 = srcn[threadIdx.x + 256];
                ra2 = srcn[threadIdx.x + 512];
            } else {
                rb0 = srcn[threadIdx.x];
                rb1 = srcn[threadIdx.x + 256];
                rb2 = srcn[threadIdx.x + 512];
            }
        }
        int oh0 = (bg * K1_CH + i) * K1_R;
        float* yb = y1 + (size_t)m * C1H * C1W + (size_t)oh0 * C1W;
        for (int o = threadIdx.x; o < K1_R * C1W; o += 256) {
            int lo = o / C1W, ow = o % C1W;
            const float* xp = sm + (3 * lo) * WGN + ow * 2;
            float acc = bb;
#pragma unroll
            for (int r = 0; r < 3; r++)
#pragma unroll
                for (int c = 0; c < 3; c++) acc += w[r * 3 + c] * xp[r * WGN + c];
            yb[o] = acc;
            s += acc; ss += (double)acc * (double)acc;
        }
        __syncthreads();
    }
    // vint for m = blockIdx.x (first 64 blocks), independent of conv path
    if (blockIdx.x < MM) {
        int mv = blockIdx.x;
        int b = mv >> 3;
        if (threadIdx.x < NP) {
            int n = threadIdx.x;
            float t = cv[(mv * NP + n) * 2 + 0];
            float v = cv[(mv * NP + n) * 2 + 1];
            float dt = 7000.0f / 255.0f;
            tt[n] = t / dt;
            float vmin = VMM[b * 2], vmax = VMM[b * 2 + 1];
            float dv = (vmax - vmin) / 255.0f;
            vv[n] = (v - vmin) / dv;
        }
        __syncthreads();
        int h = threadIdx.x;
        float x = (float)h;
        float val;
        if (x <= tt[0]) val = vv[0];
        else if (x >= tt[NP - 1]) val = vv[NP - 1];
        else {
            int i = 1;
            while (i < NP - 1 && tt[i] <= x) i++;
            float d = tt[i] - tt[i - 1];
            val = (d != 0.f) ? vv[i - 1] + (x - tt[i - 1]) / d * (vv[i] - vv[i - 1]) : vv[i];
        }
        int vi = (int)val;
        vint[mv * HH + h] = max(0, min(WCN - 1, vi));
    }
    blockStore2(s, ss, &sums[P1S], &sums[P1SS]);
}

// ---- K2: BN1-act + maxpool3/5 (separable, LDS) + conv2 + BN2 partials ----
__global__ void k_fused2(const float* __restrict__ y1, const double* __restrict__ sums_r,
                         const float* __restrict__ g1, const float* __restrict__ be1,
                         const float* __restrict__ w2, const float* __restrict__ b2,
                         float* __restrict__ y2, double* __restrict__ sums) {
    __shared__ float sact[F2_NRMAX][32];
    __shared__ float sr3[F2_NRMAX][32];
    __shared__ float sr5[F2_NRMAX][32];
    __shared__ float2 absh;
    bn_fold(&sums_r[P1S], &sums_r[P1SS], G1, g1, 0, be1, (double)N1, &absh, 0);
    __syncthreads();
    float2 ab1 = absh;
    int m   = blockIdx.x / F2_NCH;
    int ch  = blockIdx.x % F2_NCH;
    int oh0 = ch * F2_OH;
    int OHa = min(F2_OH, C2H - oh0);
    int NR  = 3 * OHa + 4;
    int gl0 = 3 * oh0 - 2;
    const float* yp = y1 + (size_t)m * C1H * C1W;
    for (int i = threadIdx.x; i < NR * C1W; i += blockDim.x) {
        int l = i / C1W, w = i % C1W;
        int gr = gl0 + l;
        float v = -INFINITY;
        if (gr >= 0 && gr < C1H) {
            v = ab1.x * yp[gr * C1W + w] + ab1.y;
            v = v >= 0.f ? v : 0.1f * v;
        }
        sact[l][w] = v;
    }
    __syncthreads();
    for (int i = threadIdx.x; i < NR * C1W; i += blockDim.x) {
        int l = i / C1W, w = i % C1W;
        int wl1 = max(w - 1, 0), wr1 = min(w + 1, C1W - 1);
        int wl2 = max(w - 2, 0), wr2 = min(w + 2, C1W - 1);
        float c  = sact[l][w];
        float m3 = fmaxf(fmaxf(sact[l][wl1], c), sact[l][wr1]);
        float m5 = fmaxf(fmaxf(m3, sact[l][wl2]), sact[l][wr2]);
        sr3[l][w] = m3;
        sr5[l][w] = m5;
    }
    __syncthreads();
    double s0 = 0, ss0 = 0, s1 = 0, ss1 = 0;
    for (int o = threadIdx.x; o < OHa * C2W; o += blockDim.x) {
        int lo = o / C2W, ow = o % C2W;
        float a0 = b2[0], acc1 = b2[1];
#pragma unroll
        for (int i = 0; i < 3; i++) {
            int l = 3 * lo + 2 + i;
#pragma unroll
            for (int j = 0; j < 3; j++) {
                int wc = 2 * ow + j;
                float v0 = sact[l][wc];
                float v1 = fmaxf(fmaxf(sr3[l - 1][wc], sr3[l][wc]), sr3[l + 1][wc]);
                float v2 = fmaxf(fmaxf(fmaxf(sr5[l - 2][wc], sr5[l - 1][wc]), sr5[l][wc]),
                                 fmaxf(sr5[l + 1][wc], sr5[l + 2][wc]));
                int ki = i * 3 + j;
                a0   += w2[ki] * v0 + w2[9 + ki] * v1 + w2[18 + ki] * v2;
                acc1 += w2[27 + ki] * v0 + w2[36 + ki] * v1 + w2[45 + ki] * v2;
            }
        }
        size_t ob = (size_t)m * (2 * C2H * C2W) + (size_t)(oh0 + lo) * C2W + ow;
        y2[ob] = a0;
        y2[ob + C2H * C2W] = acc1;
        s0 += a0; ss0 += (double)a0 * a0;
        s1 += acc1; ss1 += (double)acc1 * acc1;
    }
    blockStore2(s0, ss0, &sums[P2S0], &sums[P2SS0]);
    blockStore2(s1, ss1, &sums[P2S1], &sums[P2SS1]);
}

// ---- K3: conv3 (1x2x3x2, stride 3x2), BN2-act inline + BN3 partials ----
__global__ void k_conv3(const float* __restrict__ y2, const double* __restrict__ sums_r,
                        const float* __restrict__ g2, const float* __restrict__ be2,
                        const float* __restrict__ w3, const float* __restrict__ b3,
                        float* __restrict__ y3, double* __restrict__ sums) {
    __shared__ float2 absh[2];
    bn_fold(&sums_r[P2S0], &sums_r[P2SS0], G2, g2, 0, be2, (double)N2, &absh[0], 0);
    bn_fold(&sums_r[P2S1], &sums_r[P2SS1], G2, g2, 1, be2, (double)N2, &absh[1], 1);
    __syncthreads();
    float2 ab20 = absh[0], ab21 = absh[1];
    double s = 0, ss = 0;
    int idx = blockIdx.x * 256 + threadIdx.x;
    if (idx < N3) {
        int ow = idx % C3W;
        int t2 = idx / C3W;
        int oh = t2 % C3H;
        int m  = t2 / C3H;
        float acc = b3[0];
#pragma unroll
        for (int i = 0; i < 2; i++) {
            float aa = i ? ab21.x : ab20.x, bb = i ? ab21.y : ab20.y;
            const float* cp = y2 + (size_t)m * (2 * C2H * C2W) + (size_t)i * C2H * C2W
                              + (size_t)(oh * 3) * C2W + ow * 2;
#pragma unroll
            for (int r = 0; r < 3; r++)
#pragma unroll
                for (int c = 0; c < 2; c++) {
                    float v = aa * cp[r * C2W + c] + bb;
                    v = v >= 0.f ? v : 0.1f * v;
                    acc += w3[i * 6 + r * 2 + c] * v;
                }
        }
        y3[idx] = acc;
        s = acc; ss = (double)acc * acc;
    }
    blockStore2(s, ss, &sums[P3S], &sums[P3SS]);
}

// ---- K5a: genr-on-the-fly (BN3-act + 7-tap resize of y3) -> mix tile
//      -> convf -> y5 + BNf partials ----
__global__ void k_mixA(const float* __restrict__ y3, const int* __restrict__ vint,
                       const double* __restrict__ sums_r,
                       const float* __restrict__ g3, const float* __restrict__ be3,
                       const float* __restrict__ wf, const float* __restrict__ bf,
                       float* __restrict__ y5, double* __restrict__ sums) {
    __shared__ float tile[MC_TH + 2][RWN + 2];
    __shared__ float Grow[MC_TH + 2];
    __shared__ float2 absh;
    bn_fold(&sums_r[P3S], &sums_r[P3SS], G3, g3, 0, be3, (double)N3, &absh, 0);
    int b   = blockIdx.x / (RHN / MC_TH);
    int h0  = (blockIdx.x % (RHN / MC_TH)) * MC_TH;
    for (int i = threadIdx.x; i < (MC_TH + 2) * (RWN + 2); i += 256)
        ((float*)tile)[i] = 0.f;
    if (threadIdx.x < MC_TH + 2) Grow[threadIdx.x] = 0.f;
    __syncthreads();
    float2 ab3 = absh;
    if (threadIdx.x < (MC_TH + 2) * KG) {
        int r = threadIdx.x / KG, k = threadIdx.x % KG;
        int h = h0 - 1 + r;
        if (h >= 0 && h < RHN) {
            int m = b * KG + k;
            // genr[m][h] on the fly: BN3-act of y3 row pair, 7-tap col mix
            const float cw0 = 4.f / 37.f, cw1 = 5.f / 37.f, cw2 = 6.f / 37.f, cw3 = 7.f / 37.f;
            const float cw[7] = { cw0, cw1, cw2, cw3, cw2, cw1, cw0 };
            float shg = (h + 0.5f) * (113.0f / 1024.0f) - 0.5f;
            float flg = floorf(shg);
            float frg = shg - flg;
            int gi0 = (int)flg, gi1 = gi0 + 1;
            gi0 = max(0, min(C3H - 1, gi0));
            gi1 = max(0, min(C3H - 1, gi1));
            const float* yp0 = y3 + (size_t)m * (C3H * C3W) + gi0 * C3W;
            const float* yp1 = y3 + (size_t)m * (C3H * C3W) + gi1 * C3W;
            float g = 0.f;
#pragma unroll
            for (int x = 0; x < 7; x++) {
                float t0 = ab3.x * yp0[x] + ab3.y;
                t0 = t0 >= 0.f ? t0 : 0.1f * t0;
                float t1 = ab3.x * yp1[x] + ab3.y;
                t1 = t1 >= 0.f ? t1 : 0.1f * t1;
                g += cw[x] * ((1.f - frg) * t0 + frg * t1);
            }
            atomicAdd(&Grow[r], g);
            float sh = (h + 0.5f) * 0.25f - 0.5f;
            float fl = floorf(sh);
            float fh = sh - fl;
            int ih0 = (int)fl, ih1 = ih0 + 1;
            ih0 = max(0, min(HH - 1, ih0));
            ih1 = max(0, min(HH - 1, ih1));
            int vv2[2] = { vint[m * HH + ih0], vint[m * HH + ih1] };
            float aa[2] = { 0.9f * g * (1.f - fh), 0.9f * g * fh };
#pragma unroll
            for (int t = 0; t < 2; t++) {
                int v = vv2[t]; float A = aa[t];
                if (v == 0) {
                    atomicAdd(&tile[r][1 + 0], A);
                    atomicAdd(&tile[r][1 + 1], 0.75f * A);
                    atomicAdd(&tile[r][1 + 2], 0.25f * A);
                } else if (v == WCN - 1) {
                    atomicAdd(&tile[r][1 + 509], 0.25f * A);
                    atomicAdd(&tile[r][1 + 510], 0.75f * A);
                    atomicAdd(&tile[r][1 + 511], A);
                } else {
                    atomicAdd(&tile[r][1 + 2 * v - 1], 0.25f * A);
                    atomicAdd(&tile[r][1 + 2 * v],     0.75f * A);
                    atomicAdd(&tile[r][1 + 2 * v + 1], 0.75f * A);
                    atomicAdd(&tile[r][1 + 2 * v + 2], 0.25f * A);
                }
            }
        }
    }
    __syncthreads();
    for (int i = threadIdx.x; i < (MC_TH + 2) * RWN; i += 256) {
        int r = i / RWN, w = i % RWN;
        int h = h0 - 1 + r;
        if (h >= 0 && h < RHN) tile[r][w + 1] += 0.01f * Grow[r];
    }
    __syncthreads();
    float w[9];
#pragma unroll
    for (int i = 0; i < 9; i++) w[i] = wf[i];
    float bb = bf[0];
    double s = 0, ss = 0;
    for (int o = threadIdx.x; o < MC_TH * RWN; o += 256) {
        int lr = o >> 9, x = o & (RWN - 1);
        float acc = bb;
#pragma unroll
        for (int dr = 0; dr < 3; dr++)
#pragma unroll
            for (int dc = 0; dc < 3; dc++)
                acc += w[dr * 3 + dc] * tile[lr + dr][x + dc];
        y5[((size_t)b * RHN + (h0 + lr)) * RWN + x] = acc;
        s += acc; ss += (double)acc * acc;
    }
    blockStore2(s, ss, &sums[PFS], &sums[PFSS]);
}

// ---- K5b: BNf affine + LReLU over y5 -> out (vectorized) ----
__global__ void k_bnf(const float* __restrict__ y5, const double* __restrict__ sums_r,
                      const float* __restrict__ gf, const float* __restrict__ bef,
                      float* __restrict__ out) {
    __shared__ float2 absh;
    bn_fold(&sums_r[PFS], &sums_r[PFSS], G5, gf, 0, bef, (double)NF, &absh, 0);
    __syncthreads();
    float2 abf = absh;
    const float4* src = (const float4*)y5;
    float4* dst = (float4*)out;
    int base = blockIdx.x * 256 + threadIdx.x;
#pragma unroll
    for (int j = 0; j < 8; j++) {
        int i = base + j * (G6 * 256);
        float4 v = src[i];
        float a0 = abf.x * v.x + abf.y;
        float a1 = abf.x * v.y + abf.y;
        float a2 = abf.x * v.z + abf.y;
        float a3 = abf.x * v.w + abf.y;
        v.x = a0 >= 0.f ? a0 : 0.1f * a0;
        v.y = a1 >= 0.f ? a1 : 0.1f * a1;
        v.z = a2 >= 0.f ? a2 : 0.1f * a2;
        v.w = a3 >= 0.f ? a3 : 0.1f * a3;
        dst[i] = v;
    }
}

extern "C" void kernel_launch(void* const* d_in, const int* in_sizes, int n_in,
                              void* d_out, int out_size, void* d_ws, size_t ws_size,
                              hipStream_t stream) {
    const float* gather = (const float*)d_in[0];
    const float* cv     = (const float*)d_in[1];
    const float* VMM    = (const float*)d_in[2];
    const float* w1 = (const float*)d_in[3];
    const float* b1 = (const float*)d_in[4];
    const float* g1 = (const float*)d_in[5];
    const float* be1 = (const float*)d_in[6];
    const float* w2 = (const float*)d_in[7];
    const float* b2 = (const float*)d_in[8];
    const float* g2 = (const float*)d_in[9];
    const float* be2 = (const float*)d_in[10];
    const float* w3 = (const float*)d_in[11];
    const float* b3 = (const float*)d_in[12];
    const float* g3 = (const float*)d_in[13];
    const float* be3 = (const float*)d_in[14];
    const float* wf = (const float*)d_in[15];
    const float* bf = (const float*)d_in[16];
    const float* gf = (const float*)d_in[17];
    const float* bef = (const float*)d_in[18];
    float* out = (float*)d_out;

    char* ws = (char*)d_ws;
    double* sums = (double*)ws;
    int*   vint  = (int*)(ws + OFF_VINT);
    float* y1    = (float*)(ws + OFF_Y1);
    float* y2    = (float*)(ws + OFF_Y2);
    float* y3    = (float*)(ws + OFF_Y3);
    float* y5    = (float*)(ws + OFF_Y5);

    k_conv1<<<G1, 256, 0, stream>>>(gather, cv, VMM, w1, b1, y1, vint, sums);
    k_fused2<<<G2, 256, 0, stream>>>(y1, sums, g1, be1, w2, b2, y2, sums);
    k_conv3<<<G3, 256, 0, stream>>>(y2, sums, g2, be2, w3, b3, y3, sums);
    k_mixA<<<G5, 256, 0, stream>>>(y3, vint, sums, g3, be3, wf, bf, y5, sums);
    k_bnf<<<G6, 256, 0, stream>>>(y5, sums, gf, bef, out);
}